// Round 8
// baseline (186.192 us; speedup 1.0000x reference)
//
#include <hip/hip_runtime.h>
#include <math.h>

#define B_  8
#define C_  64
#define T_  64
#define HW_ 3136      // 56*56
#define E_  128
#define K_  8
#define NS_ 500

// ---------------- Kernel 1: avg+max reduce over the HW plane ----------------
// grid = B*C = 2048 blocks, 256 threads (4 waves). Wave w owns t = w, w+4, ...
// Each wave tree-reduces whole planes: no LDS, no __syncthreads, 12-13
// pipelined float4 loads per plane, 16 planes per wave.
__global__ __launch_bounds__(256) void k_reduce(const float* __restrict__ x,
                                                float* __restrict__ feat) {
    int bc   = blockIdx.x;           // b*64 + c
    int b    = bc >> 6;
    int c    = bc & 63;
    int wid  = threadIdx.x >> 6;
    int lane = threadIdx.x & 63;
    for (int t = wid; t < T_; t += 4) {
        const float4* p = (const float4*)(x + ((size_t)bc * T_ + t) * HW_);
        float s = 0.f, m = -INFINITY;
        for (int i = lane; i < HW_ / 4; i += 64) {
            float4 v = p[i];
            s += v.x + v.y + v.z + v.w;
            m = fmaxf(m, fmaxf(fmaxf(v.x, v.y), fmaxf(v.z, v.w)));
        }
        for (int o = 32; o; o >>= 1) {
            s += __shfl_down(s, o);
            m = fmaxf(m, __shfl_down(m, o));
        }
        if (lane == 0) {
            float* fr = feat + (size_t)(b * T_ + t) * E_;
            fr[c]      = s / 3136.0f;   // mean
            fr[C_ + c] = m;             // max
        }
    }
}

// ---------------- Kernel 2: LayerNorm + matvec(128x128) + gelu --------------
// grid = B*T blocks, 128 threads (one row each). First 32 blocks also zero
// the indicator counts (4096 floats) consumed by k_topk's atomics.
__global__ __launch_bounds__(128) void k_mlp1(const float* __restrict__ feat,
                                              const float* __restrict__ ln_w,
                                              const float* __restrict__ ln_b,
                                              const float* __restrict__ w1,
                                              const float* __restrict__ b1,
                                              float* __restrict__ h,
                                              float* __restrict__ ind) {
    int r = blockIdx.x;          // b*T + t
    int j = threadIdx.x;
    if (r < 32) ind[r * 128 + j] = 0.f;
    __shared__ float nr[E_];
    __shared__ float red[2];
    float f = feat[(size_t)r * E_ + j];
    // mean
    float s = f;
    for (int o = 32; o; o >>= 1) s += __shfl_down(s, o);
    if ((j & 63) == 0) red[j >> 6] = s;
    __syncthreads();
    float mu = (red[0] + red[1]) * (1.0f / 128.0f);
    __syncthreads();
    // var
    float d = f - mu;
    s = d * d;
    for (int o = 32; o; o >>= 1) s += __shfl_down(s, o);
    if ((j & 63) == 0) red[j >> 6] = s;
    __syncthreads();
    float var = (red[0] + red[1]) * (1.0f / 128.0f);
    float n = d / sqrtf(var + 1e-5f) * ln_w[j] + ln_b[j];
    nr[j] = n;
    __syncthreads();
    float acc = b1[j];
    #pragma unroll 8
    for (int i = 0; i < E_; i++) acc = fmaf(nr[i], w1[i * E_ + j], acc);
    // exact gelu
    float g = 0.5f * acc * (1.0f + erff(acc * 0.70710678118654752f));
    h[(size_t)r * E_ + j] = g;
}

// ------- JAX-exact noise: PARTITIONABLE threefry2x32(key=(0,42)) + erfinv ---
// counts = (hi=0, lo=i); bits = out0 ^ out1 (XOR-fold, verified round 5).
__device__ inline float jax_normal(unsigned idx) {
    unsigned x0 = 0u;      // counts_hi
    unsigned x1 = idx;     // counts_lo
    const unsigned k0 = 0u, k1 = 42u;
    const unsigned k2 = 0x1BD11BDAu ^ k0 ^ k1;
    x0 += k0; x1 += k1;
#define R_(r) { x0 += x1; x1 = (x1 << r) | (x1 >> (32 - r)); x1 ^= x0; }
    R_(13) R_(15) R_(26) R_(6)
    x0 += k1; x1 += k2 + 1u;
    R_(17) R_(29) R_(16) R_(24)
    x0 += k2; x1 += k0 + 2u;
    R_(13) R_(15) R_(26) R_(6)
    x0 += k0; x1 += k1 + 3u;
    R_(17) R_(29) R_(16) R_(24)
    x0 += k1; x1 += k2 + 4u;
    R_(13) R_(15) R_(26) R_(6)
    x0 += k2; x1 += k0 + 5u;
#undef R_
    unsigned bits = x0 ^ x1;
    float f = __uint_as_float((bits >> 9) | 0x3F800000u) - 1.0f;
    const float lo = -0.99999994f;
    float u = f * 2.0f + lo;
    u = fmaxf(lo, u);
    float w = -log1pf(-u * u);
    float p;
    if (w < 5.0f) {
        w -= 2.5f;
        p = 2.81022636e-08f;
        p = fmaf(p, w, 3.43273939e-07f);
        p = fmaf(p, w, -3.5233877e-06f);
        p = fmaf(p, w, -4.39150654e-06f);
        p = fmaf(p, w, 0.00021858087f);
        p = fmaf(p, w, -0.00125372503f);
        p = fmaf(p, w, -0.00417768164f);
        p = fmaf(p, w, 0.246640727f);
        p = fmaf(p, w, 1.50140941f);
    } else {
        w = sqrtf(w) - 3.0f;
        p = -0.000200214257f;
        p = fmaf(p, w, 0.000100950558f);
        p = fmaf(p, w, 0.00134934322f);
        p = fmaf(p, w, -0.00367342844f);
        p = fmaf(p, w, 0.00573950773f);
        p = fmaf(p, w, -0.0076224613f);
        p = fmaf(p, w, 0.00943887047f);
        p = fmaf(p, w, 1.00167406f);
        p = fmaf(p, w, 2.83297682f);
    }
    return 1.41421356237f * (p * u);
}

// ------- Kernel 3 (fused): score recompute + 4 perturbed top-k samples -----
// grid = B*125 blocks, 256 threads (4 waves = 4 samples). Each block
// recomputes its b's scores from h (32 KB/b, L2-resident, shared by 125
// blocks) with the round-5 reduction order.
__global__ __launch_bounds__(256) void k_topk(const float* __restrict__ h,
                                              const float* __restrict__ w2,
                                              const float* __restrict__ b2,
                                              float* __restrict__ ind) {
    int blk  = blockIdx.x;
    int b    = blk / 125;
    int loc  = blk - b * 125;
    int tid  = threadIdx.x;
    int wid  = tid >> 6;
    int lane = tid & 63;
    __shared__ float gm[64];
    __shared__ float sv[64];
    __shared__ float gdot_s, lo_s, hi_s;
    const float* hb = h + (size_t)b * T_ * E_;

    // gmean over t of h[..., 64+i]  (serial t order == round 5)
    if (tid < 64) {
        float s = 0.f;
        for (int t = 0; t < T_; t++) s += hb[t * E_ + 64 + tid];
        gm[tid] = s * (1.0f / 64.0f);
    }
    __syncthreads();
    if (wid == 0) {
        float s = gm[lane] * w2[64 + lane];
        for (int o = 32; o; o >>= 1) s += __shfl_down(s, o);
        if (lane == 0) gdot_s = s;
    }
    __syncthreads();
    if (tid < 64) {
        float acc = 0.f;
        for (int i = 0; i < 64; i++)
            acc = fmaf(hb[tid * E_ + i], w2[i], acc);
        float pre = acc + gdot_s + b2[0];
        sv[tid] = 0.5f * pre * (1.0f + erff(pre * 0.70710678118654752f));
    }
    __syncthreads();
    if (wid == 0) {
        float v = sv[lane];
        float mn = v, mx = v;
        for (int o = 32; o; o >>= 1) {
            mn = fminf(mn, __shfl_down(mn, o));
            mx = fmaxf(mx, __shfl_down(mx, o));
        }
        if (lane == 0) { lo_s = mn; hi_s = mx; }
    }
    __syncthreads();
    float myscore = (sv[lane] - lo_s) / (hi_s - lo_s + 1e-5f);

    // one sample per wave
    int s = loc * 4 + wid;      // < 500
    float nrm = jax_normal((unsigned)((b * NS_ + s) * 64 + lane));
    float v = myscore + nrm * 0.05f;
    int rank = 0;
    for (int j = 0; j < 64; j++) {
        float o = __shfl(v, j);
        rank += (o > v) || (o == v && j < lane);
    }
    bool sel = rank < K_;
    unsigned long long m = __ballot(sel);
    if (sel) {
        int pos = __popcll(m & ((1ull << lane) - 1ull));
        atomicAdd(&ind[b * 512 + pos * 64 + lane], 1.0f);
    }
}

// ---------------- Kernel 4: weighted gather over t --------------------------
// out[b,c,k,hw] = sum_t w[b,k,t] * x[b,c,t,hw];  grid = 1568 x 256,
// one float4 per thread, 8 accumulators, skip all-zero t (uniform per block).
__global__ __launch_bounds__(256) void k_einsum(const float* __restrict__ x,
                                                const float* __restrict__ ind,
                                                float* __restrict__ out) {
    int gid   = blockIdx.x * 256 + threadIdx.x;
    int plane = gid / 784;                  // b*C + c
    int i     = gid - plane * 784;          // float4 index in plane
    int b     = plane >> 6;
    int tid   = threadIdx.x;
    __shared__ float w[K_ * T_];
    __shared__ float wsum[T_];
    w[tid]       = ind[b * 512 + tid]       / 500.0f;
    w[tid + 256] = ind[b * 512 + 256 + tid] / 500.0f;
    __syncthreads();
    if (tid < 64) {
        float s = 0.f;
        #pragma unroll
        for (int k = 0; k < K_; k++) s += w[k * 64 + tid];
        wsum[tid] = s;
    }
    __syncthreads();

    const float4* xp = (const float4*)x + (size_t)plane * (T_ * 784) + i;
    float4 acc[K_];
    #pragma unroll
    for (int k = 0; k < K_; k++) acc[k] = make_float4(0.f, 0.f, 0.f, 0.f);

    for (int t = 0; t < T_; t++) {
        if (wsum[t] != 0.f) {
            float4 v = xp[(size_t)t * 784];
            #pragma unroll
            for (int k = 0; k < K_; k++) {
                float wk = w[k * 64 + t];
                acc[k].x = fmaf(wk, v.x, acc[k].x);
                acc[k].y = fmaf(wk, v.y, acc[k].y);
                acc[k].z = fmaf(wk, v.z, acc[k].z);
                acc[k].w = fmaf(wk, v.w, acc[k].w);
            }
        }
    }
    float4* op = (float4*)out + (size_t)plane * (K_ * 784) + i;
    #pragma unroll
    for (int k = 0; k < K_; k++) op[(size_t)k * 784] = acc[k];
}

extern "C" void kernel_launch(void* const* d_in, const int* in_sizes, int n_in,
                              void* d_out, int out_size, void* d_ws, size_t ws_size,
                              hipStream_t stream) {
    (void)in_sizes; (void)n_in; (void)out_size; (void)ws_size;
    const float* x    = (const float*)d_in[0];
    const float* ln_w = (const float*)d_in[1];
    const float* ln_b = (const float*)d_in[2];
    const float* w1   = (const float*)d_in[3];
    const float* b1   = (const float*)d_in[4];
    const float* w2   = (const float*)d_in[5];
    const float* b2   = (const float*)d_in[6];
    float* out = (float*)d_out;
    float* ws  = (float*)d_ws;
    float* feat = ws;              // B*T*E = 65536 floats
    float* h    = ws + 65536;      // B*T*E = 65536 floats
    float* ind  = ws + 131072;     // B*K*T = 4096 floats

    hipLaunchKernelGGL(k_reduce, dim3(B_ * C_),      dim3(256), 0, stream, x, feat);
    hipLaunchKernelGGL(k_mlp1,   dim3(B_ * T_),      dim3(128), 0, stream,
                       feat, ln_w, ln_b, w1, b1, h, ind);
    hipLaunchKernelGGL(k_topk,   dim3(B_ * 125),     dim3(256), 0, stream,
                       h, w2, b2, ind);
    hipLaunchKernelGGL(k_einsum, dim3(1568),         dim3(256), 0, stream, x, ind, out);
}

// Round 9
// 134.826 us; speedup vs baseline: 1.3810x; 1.3810x over previous
//
#include <hip/hip_runtime.h>
#include <math.h>

#define B_  8
#define C_  64
#define T_  64
#define HW_ 3136      // 56*56
#define E_  128
#define K_  8
#define NS_ 500

// ---------------- Kernel 1: avg+max reduce over the HW plane ----------------
// grid = B*C*T/2 = 16384 blocks, 128 threads (2 waves). Wave w reduces plane
// u = 2*blockIdx.x + w entirely in-wave: 12-13 independent float4 loads per
// lane, ONE shuffle-reduce + store, no LDS, no barriers, block exits.
__global__ __launch_bounds__(128) void k_reduce(const float* __restrict__ x,
                                                float* __restrict__ feat) {
    int u    = blockIdx.x * 2 + (threadIdx.x >> 6);
    int lane = threadIdx.x & 63;
    int t  = u & 63;
    int bc = u >> 6;
    int c  = bc & 63;
    int b  = bc >> 6;
    const float4* p = (const float4*)(x + (size_t)u * HW_);
    float s = 0.f, m = -INFINITY;
    for (int i = lane; i < HW_ / 4; i += 64) {
        float4 v = p[i];
        s += v.x + v.y + v.z + v.w;
        m = fmaxf(m, fmaxf(fmaxf(v.x, v.y), fmaxf(v.z, v.w)));
    }
    for (int o = 32; o; o >>= 1) {
        s += __shfl_down(s, o);
        m = fmaxf(m, __shfl_down(m, o));
    }
    if (lane == 0) {
        float* fr = feat + (size_t)(b * T_ + t) * E_;
        fr[c]      = s / 3136.0f;   // mean
        fr[C_ + c] = m;             // max
    }
}

// ---------------- Kernel 2: LayerNorm + matvec(128x128) + gelu --------------
// grid = B*T blocks, 128 threads (one row each). First 32 blocks also zero
// the indicator counts (4096 floats) consumed by k_topk's atomics.
__global__ __launch_bounds__(128) void k_mlp1(const float* __restrict__ feat,
                                              const float* __restrict__ ln_w,
                                              const float* __restrict__ ln_b,
                                              const float* __restrict__ w1,
                                              const float* __restrict__ b1,
                                              float* __restrict__ h,
                                              float* __restrict__ ind) {
    int r = blockIdx.x;          // b*T + t
    int j = threadIdx.x;
    if (r < 32) ind[r * 128 + j] = 0.f;
    __shared__ float nr[E_];
    __shared__ float red[2];
    float f = feat[(size_t)r * E_ + j];
    // mean
    float s = f;
    for (int o = 32; o; o >>= 1) s += __shfl_down(s, o);
    if ((j & 63) == 0) red[j >> 6] = s;
    __syncthreads();
    float mu = (red[0] + red[1]) * (1.0f / 128.0f);
    __syncthreads();
    // var
    float d = f - mu;
    s = d * d;
    for (int o = 32; o; o >>= 1) s += __shfl_down(s, o);
    if ((j & 63) == 0) red[j >> 6] = s;
    __syncthreads();
    float var = (red[0] + red[1]) * (1.0f / 128.0f);
    float n = d / sqrtf(var + 1e-5f) * ln_w[j] + ln_b[j];
    nr[j] = n;
    __syncthreads();
    float acc = b1[j];
    #pragma unroll 8
    for (int i = 0; i < E_; i++) acc = fmaf(nr[i], w1[i * E_ + j], acc);
    // exact gelu
    float g = 0.5f * acc * (1.0f + erff(acc * 0.70710678118654752f));
    h[(size_t)r * E_ + j] = g;
}

// ------- JAX-exact noise: PARTITIONABLE threefry2x32(key=(0,42)) + erfinv ---
// counts = (hi=0, lo=i); bits = out0 ^ out1 (XOR-fold, verified round 5).
__device__ inline float jax_normal(unsigned idx) {
    unsigned x0 = 0u;      // counts_hi
    unsigned x1 = idx;     // counts_lo
    const unsigned k0 = 0u, k1 = 42u;
    const unsigned k2 = 0x1BD11BDAu ^ k0 ^ k1;
    x0 += k0; x1 += k1;
#define R_(r) { x0 += x1; x1 = (x1 << r) | (x1 >> (32 - r)); x1 ^= x0; }
    R_(13) R_(15) R_(26) R_(6)
    x0 += k1; x1 += k2 + 1u;
    R_(17) R_(29) R_(16) R_(24)
    x0 += k2; x1 += k0 + 2u;
    R_(13) R_(15) R_(26) R_(6)
    x0 += k0; x1 += k1 + 3u;
    R_(17) R_(29) R_(16) R_(24)
    x0 += k1; x1 += k2 + 4u;
    R_(13) R_(15) R_(26) R_(6)
    x0 += k2; x1 += k0 + 5u;
#undef R_
    unsigned bits = x0 ^ x1;
    float f = __uint_as_float((bits >> 9) | 0x3F800000u) - 1.0f;
    const float lo = -0.99999994f;
    float u = f * 2.0f + lo;
    u = fmaxf(lo, u);
    float w = -log1pf(-u * u);
    float p;
    if (w < 5.0f) {
        w -= 2.5f;
        p = 2.81022636e-08f;
        p = fmaf(p, w, 3.43273939e-07f);
        p = fmaf(p, w, -3.5233877e-06f);
        p = fmaf(p, w, -4.39150654e-06f);
        p = fmaf(p, w, 0.00021858087f);
        p = fmaf(p, w, -0.00125372503f);
        p = fmaf(p, w, -0.00417768164f);
        p = fmaf(p, w, 0.246640727f);
        p = fmaf(p, w, 1.50140941f);
    } else {
        w = sqrtf(w) - 3.0f;
        p = -0.000200214257f;
        p = fmaf(p, w, 0.000100950558f);
        p = fmaf(p, w, 0.00134934322f);
        p = fmaf(p, w, -0.00367342844f);
        p = fmaf(p, w, 0.00573950773f);
        p = fmaf(p, w, -0.0076224613f);
        p = fmaf(p, w, 0.00943887047f);
        p = fmaf(p, w, 1.00167406f);
        p = fmaf(p, w, 2.83297682f);
    }
    return 1.41421356237f * (p * u);
}

// ------- Kernel 3 (fused): score recompute + 4 perturbed top-k samples -----
// grid = B*125 blocks, 256 threads (4 waves = 4 samples). Each block
// recomputes its b's scores from h (32 KB/b, L2-resident, shared by 125
// blocks) with the round-5 reduction order.
__global__ __launch_bounds__(256) void k_topk(const float* __restrict__ h,
                                              const float* __restrict__ w2,
                                              const float* __restrict__ b2,
                                              float* __restrict__ ind) {
    int blk  = blockIdx.x;
    int b    = blk / 125;
    int loc  = blk - b * 125;
    int tid  = threadIdx.x;
    int wid  = tid >> 6;
    int lane = tid & 63;
    __shared__ float gm[64];
    __shared__ float sv[64];
    __shared__ float gdot_s, lo_s, hi_s;
    const float* hb = h + (size_t)b * T_ * E_;

    // gmean over t of h[..., 64+i]  (serial t order == round 5)
    if (tid < 64) {
        float s = 0.f;
        for (int t = 0; t < T_; t++) s += hb[t * E_ + 64 + tid];
        gm[tid] = s * (1.0f / 64.0f);
    }
    __syncthreads();
    if (wid == 0) {
        float s = gm[lane] * w2[64 + lane];
        for (int o = 32; o; o >>= 1) s += __shfl_down(s, o);
        if (lane == 0) gdot_s = s;
    }
    __syncthreads();
    if (tid < 64) {
        float acc = 0.f;
        for (int i = 0; i < 64; i++)
            acc = fmaf(hb[tid * E_ + i], w2[i], acc);
        float pre = acc + gdot_s + b2[0];
        sv[tid] = 0.5f * pre * (1.0f + erff(pre * 0.70710678118654752f));
    }
    __syncthreads();
    if (wid == 0) {
        float v = sv[lane];
        float mn = v, mx = v;
        for (int o = 32; o; o >>= 1) {
            mn = fminf(mn, __shfl_down(mn, o));
            mx = fmaxf(mx, __shfl_down(mx, o));
        }
        if (lane == 0) { lo_s = mn; hi_s = mx; }
    }
    __syncthreads();
    float myscore = (sv[lane] - lo_s) / (hi_s - lo_s + 1e-5f);

    // one sample per wave
    int s = loc * 4 + wid;      // < 500
    float nrm = jax_normal((unsigned)((b * NS_ + s) * 64 + lane));
    float v = myscore + nrm * 0.05f;
    int rank = 0;
    for (int j = 0; j < 64; j++) {
        float o = __shfl(v, j);
        rank += (o > v) || (o == v && j < lane);
    }
    bool sel = rank < K_;
    unsigned long long m = __ballot(sel);
    if (sel) {
        int pos = __popcll(m & ((1ull << lane) - 1ull));
        atomicAdd(&ind[b * 512 + pos * 64 + lane], 1.0f);
    }
}

// ---------------- Kernel 4: weighted gather over t --------------------------
// out[b,c,k,hw] = sum_t w[b,k,t] * x[b,c,t,hw];  grid = 1568 x 256,
// one float4 per thread, 8 accumulators, skip all-zero t (uniform per block).
__global__ __launch_bounds__(256) void k_einsum(const float* __restrict__ x,
                                                const float* __restrict__ ind,
                                                float* __restrict__ out) {
    int gid   = blockIdx.x * 256 + threadIdx.x;
    int plane = gid / 784;                  // b*C + c
    int i     = gid - plane * 784;          // float4 index in plane
    int b     = plane >> 6;
    int tid   = threadIdx.x;
    __shared__ float w[K_ * T_];
    __shared__ float wsum[T_];
    w[tid]       = ind[b * 512 + tid]       / 500.0f;
    w[tid + 256] = ind[b * 512 + 256 + tid] / 500.0f;
    __syncthreads();
    if (tid < 64) {
        float s = 0.f;
        #pragma unroll
        for (int k = 0; k < K_; k++) s += w[k * 64 + tid];
        wsum[tid] = s;
    }
    __syncthreads();

    const float4* xp = (const float4*)x + (size_t)plane * (T_ * 784) + i;
    float4 acc[K_];
    #pragma unroll
    for (int k = 0; k < K_; k++) acc[k] = make_float4(0.f, 0.f, 0.f, 0.f);

    for (int t = 0; t < T_; t++) {
        if (wsum[t] != 0.f) {
            float4 v = xp[(size_t)t * 784];
            #pragma unroll
            for (int k = 0; k < K_; k++) {
                float wk = w[k * 64 + t];
                acc[k].x = fmaf(wk, v.x, acc[k].x);
                acc[k].y = fmaf(wk, v.y, acc[k].y);
                acc[k].z = fmaf(wk, v.z, acc[k].z);
                acc[k].w = fmaf(wk, v.w, acc[k].w);
            }
        }
    }
    float4* op = (float4*)out + (size_t)plane * (K_ * 784) + i;
    #pragma unroll
    for (int k = 0; k < K_; k++) op[(size_t)k * 784] = acc[k];
}

extern "C" void kernel_launch(void* const* d_in, const int* in_sizes, int n_in,
                              void* d_out, int out_size, void* d_ws, size_t ws_size,
                              hipStream_t stream) {
    (void)in_sizes; (void)n_in; (void)out_size; (void)ws_size;
    const float* x    = (const float*)d_in[0];
    const float* ln_w = (const float*)d_in[1];
    const float* ln_b = (const float*)d_in[2];
    const float* w1   = (const float*)d_in[3];
    const float* b1   = (const float*)d_in[4];
    const float* w2   = (const float*)d_in[5];
    const float* b2   = (const float*)d_in[6];
    float* out = (float*)d_out;
    float* ws  = (float*)d_ws;
    float* feat = ws;              // B*T*E = 65536 floats
    float* h    = ws + 65536;      // B*T*E = 65536 floats
    float* ind  = ws + 131072;     // B*K*T = 4096 floats

    hipLaunchKernelGGL(k_reduce, dim3(B_ * C_ * T_ / 2), dim3(128), 0, stream, x, feat);
    hipLaunchKernelGGL(k_mlp1,   dim3(B_ * T_),          dim3(128), 0, stream,
                       feat, ln_w, ln_b, w1, b1, h, ind);
    hipLaunchKernelGGL(k_topk,   dim3(B_ * 125),         dim3(256), 0, stream,
                       h, w2, b2, ind);
    hipLaunchKernelGGL(k_einsum, dim3(1568),             dim3(256), 0, stream, x, ind, out);
}

// Round 10
// 129.624 us; speedup vs baseline: 1.4364x; 1.0401x over previous
//
#include <hip/hip_runtime.h>
#include <math.h>

#define B_  8
#define C_  64
#define T_  64
#define HW_ 3136      // 56*56
#define E_  128
#define K_  8
#define NS_ 500

// ---------------- Kernel 1: avg+max reduce over the HW plane ----------------
// grid = B*C*T blocks, 256 threads (r5/r7 winning form, reversed order).
__global__ __launch_bounds__(256) void k_reduce(const float* __restrict__ x,
                                                float* __restrict__ feat) {
    int u  = (B_ * C_ * T_ - 1) - blockIdx.x;
    int t  = u & 63;
    int bc = u >> 6;
    int c  = bc & 63;
    int b  = bc >> 6;
    const float4* p = (const float4*)(x + (size_t)u * HW_);
    float s = 0.f, m = -INFINITY;
    for (int i = threadIdx.x; i < HW_ / 4; i += 256) {
        float4 v = p[i];
        s += v.x + v.y + v.z + v.w;
        m = fmaxf(m, fmaxf(fmaxf(v.x, v.y), fmaxf(v.z, v.w)));
    }
    for (int o = 32; o; o >>= 1) {
        s += __shfl_down(s, o);
        m = fmaxf(m, __shfl_down(m, o));
    }
    __shared__ float ss[4], sm[4];
    int wid = threadIdx.x >> 6, lane = threadIdx.x & 63;
    if (lane == 0) { ss[wid] = s; sm[wid] = m; }
    __syncthreads();
    if (threadIdx.x == 0) {
        s = ss[0] + ss[1] + ss[2] + ss[3];
        m = fmaxf(fmaxf(sm[0], sm[1]), fmaxf(sm[2], sm[3]));
        float* fr = feat + (size_t)(b * T_ + t) * E_;
        fr[c]      = s / 3136.0f;   // mean
        fr[C_ + c] = m;             // max
    }
}

// ---------------- Kernel 2: LayerNorm + matvec(128x128) + gelu --------------
// grid = B*T blocks, 128 threads (one row each). First 32 blocks also zero
// the indicator counts (4096 floats) consumed by k_topk's atomics.
__global__ __launch_bounds__(128) void k_mlp1(const float* __restrict__ feat,
                                              const float* __restrict__ ln_w,
                                              const float* __restrict__ ln_b,
                                              const float* __restrict__ w1,
                                              const float* __restrict__ b1,
                                              float* __restrict__ h,
                                              float* __restrict__ ind) {
    int r = blockIdx.x;          // b*T + t
    int j = threadIdx.x;
    if (r < 32) ind[r * 128 + j] = 0.f;
    __shared__ float nr[E_];
    __shared__ float red[2];
    float f = feat[(size_t)r * E_ + j];
    // mean
    float s = f;
    for (int o = 32; o; o >>= 1) s += __shfl_down(s, o);
    if ((j & 63) == 0) red[j >> 6] = s;
    __syncthreads();
    float mu = (red[0] + red[1]) * (1.0f / 128.0f);
    __syncthreads();
    // var
    float d = f - mu;
    s = d * d;
    for (int o = 32; o; o >>= 1) s += __shfl_down(s, o);
    if ((j & 63) == 0) red[j >> 6] = s;
    __syncthreads();
    float var = (red[0] + red[1]) * (1.0f / 128.0f);
    float n = d / sqrtf(var + 1e-5f) * ln_w[j] + ln_b[j];
    nr[j] = n;
    __syncthreads();
    float acc = b1[j];
    #pragma unroll 8
    for (int i = 0; i < E_; i++) acc = fmaf(nr[i], w1[i * E_ + j], acc);
    // exact gelu
    float g = 0.5f * acc * (1.0f + erff(acc * 0.70710678118654752f));
    h[(size_t)r * E_ + j] = g;
}

// ------- JAX-exact noise: PARTITIONABLE threefry2x32(key=(0,42)) + erfinv ---
// counts = (hi=0, lo=i); bits = out0 ^ out1 (XOR-fold, verified round 5).
__device__ inline float jax_normal(unsigned idx) {
    unsigned x0 = 0u;      // counts_hi
    unsigned x1 = idx;     // counts_lo
    const unsigned k0 = 0u, k1 = 42u;
    const unsigned k2 = 0x1BD11BDAu ^ k0 ^ k1;
    x0 += k0; x1 += k1;
#define R_(r) { x0 += x1; x1 = (x1 << r) | (x1 >> (32 - r)); x1 ^= x0; }
    R_(13) R_(15) R_(26) R_(6)
    x0 += k1; x1 += k2 + 1u;
    R_(17) R_(29) R_(16) R_(24)
    x0 += k2; x1 += k0 + 2u;
    R_(13) R_(15) R_(26) R_(6)
    x0 += k0; x1 += k1 + 3u;
    R_(17) R_(29) R_(16) R_(24)
    x0 += k1; x1 += k2 + 4u;
    R_(13) R_(15) R_(26) R_(6)
    x0 += k2; x1 += k0 + 5u;
#undef R_
    unsigned bits = x0 ^ x1;
    float f = __uint_as_float((bits >> 9) | 0x3F800000u) - 1.0f;
    const float lo = -0.99999994f;
    float u = f * 2.0f + lo;
    u = fmaxf(lo, u);
    float w = -log1pf(-u * u);
    float p;
    if (w < 5.0f) {
        w -= 2.5f;
        p = 2.81022636e-08f;
        p = fmaf(p, w, 3.43273939e-07f);
        p = fmaf(p, w, -3.5233877e-06f);
        p = fmaf(p, w, -4.39150654e-06f);
        p = fmaf(p, w, 0.00021858087f);
        p = fmaf(p, w, -0.00125372503f);
        p = fmaf(p, w, -0.00417768164f);
        p = fmaf(p, w, 0.246640727f);
        p = fmaf(p, w, 1.50140941f);
    } else {
        w = sqrtf(w) - 3.0f;
        p = -0.000200214257f;
        p = fmaf(p, w, 0.000100950558f);
        p = fmaf(p, w, 0.00134934322f);
        p = fmaf(p, w, -0.00367342844f);
        p = fmaf(p, w, 0.00573950773f);
        p = fmaf(p, w, -0.0076224613f);
        p = fmaf(p, w, 0.00943887047f);
        p = fmaf(p, w, 1.00167406f);
        p = fmaf(p, w, 2.83297682f);
    }
    return 1.41421356237f * (p * u);
}

// ------- Kernel 3 (fused): score recompute + 4 perturbed top-k samples -----
// grid = B*125 blocks, 256 threads (4 waves = 4 samples). Each block
// recomputes its b's scores from h (32 KB/b, L2-resident, shared by 125
// blocks) with the round-5 reduction order.
__global__ __launch_bounds__(256) void k_topk(const float* __restrict__ h,
                                              const float* __restrict__ w2,
                                              const float* __restrict__ b2,
                                              float* __restrict__ ind) {
    int blk  = blockIdx.x;
    int b    = blk / 125;
    int loc  = blk - b * 125;
    int tid  = threadIdx.x;
    int wid  = tid >> 6;
    int lane = tid & 63;
    __shared__ float gm[64];
    __shared__ float sv[64];
    __shared__ float gdot_s, lo_s, hi_s;
    const float* hb = h + (size_t)b * T_ * E_;

    // gmean over t of h[..., 64+i]  (serial t order == round 5)
    if (tid < 64) {
        float s = 0.f;
        for (int t = 0; t < T_; t++) s += hb[t * E_ + 64 + tid];
        gm[tid] = s * (1.0f / 64.0f);
    }
    __syncthreads();
    if (wid == 0) {
        float s = gm[lane] * w2[64 + lane];
        for (int o = 32; o; o >>= 1) s += __shfl_down(s, o);
        if (lane == 0) gdot_s = s;
    }
    __syncthreads();
    if (tid < 64) {
        float acc = 0.f;
        for (int i = 0; i < 64; i++)
            acc = fmaf(hb[tid * E_ + i], w2[i], acc);
        float pre = acc + gdot_s + b2[0];
        sv[tid] = 0.5f * pre * (1.0f + erff(pre * 0.70710678118654752f));
    }
    __syncthreads();
    if (wid == 0) {
        float v = sv[lane];
        float mn = v, mx = v;
        for (int o = 32; o; o >>= 1) {
            mn = fminf(mn, __shfl_down(mn, o));
            mx = fmaxf(mx, __shfl_down(mx, o));
        }
        if (lane == 0) { lo_s = mn; hi_s = mx; }
    }
    __syncthreads();
    float myscore = (sv[lane] - lo_s) / (hi_s - lo_s + 1e-5f);

    // one sample per wave
    int s = loc * 4 + wid;      // < 500
    float nrm = jax_normal((unsigned)((b * NS_ + s) * 64 + lane));
    float v = myscore + nrm * 0.05f;
    int rank = 0;
    for (int j = 0; j < 64; j++) {
        float o = __shfl(v, j);
        rank += (o > v) || (o == v && j < lane);
    }
    bool sel = rank < K_;
    unsigned long long m = __ballot(sel);
    if (sel) {
        int pos = __popcll(m & ((1ull << lane) - 1ull));
        atomicAdd(&ind[b * 512 + pos * 64 + lane], 1.0f);
    }
}

// ---------------- Kernel 4: weighted gather over t --------------------------
// out[b,c,k,hw] = sum_t w[b,k,t] * x[b,c,t,hw];  grid = 1568 x 256.
// Wave 0 compacts the active-t set into tl[]; the main loop is branch-free
// with a manual 2-deep load prefetch so HBM latency pipelines across t.
// Summation order over t == ascending == previous rounds (bit-identical).
__global__ __launch_bounds__(256) void k_einsum(const float* __restrict__ x,
                                                const float* __restrict__ ind,
                                                float* __restrict__ out) {
    int gid   = blockIdx.x * 256 + threadIdx.x;
    int plane = gid / 784;                  // b*C + c (one b per block: 784*64 % 256 == 0)
    int i     = gid - plane * 784;          // float4 index in plane
    int b     = plane >> 6;
    int tid   = threadIdx.x;
    __shared__ float w[K_ * T_];
    __shared__ int   tl[T_];
    __shared__ int   nact_s;
    w[tid]       = ind[b * 512 + tid]       * (1.0f / 500.0f);
    w[tid + 256] = ind[b * 512 + 256 + tid] * (1.0f / 500.0f);
    __syncthreads();
    if (tid < 64) {          // exactly wave 0
        float s = 0.f;
        #pragma unroll
        for (int k = 0; k < K_; k++) s += w[k * 64 + tid];
        bool act = (s != 0.f);
        unsigned long long mb = __ballot(act);
        if (act) {
            int pos = __popcll(mb & ((1ull << tid) - 1ull));
            tl[pos] = tid;
        }
        if (tid == 0) nact_s = __popcll(mb);
    }
    __syncthreads();
    int nact = nact_s;

    const float4* xp = (const float4*)x + (size_t)plane * (T_ * 784) + i;
    float4 acc[K_];
    #pragma unroll
    for (int k = 0; k < K_; k++) acc[k] = make_float4(0.f, 0.f, 0.f, 0.f);

    float4 v = xp[(size_t)tl[0] * 784];     // nact >= K always
    for (int j = 0; j < nact; j++) {
        int tc = tl[j];
        float4 vn = v;
        if (j + 1 < nact) vn = xp[(size_t)tl[j + 1] * 784];   // prefetch next
        #pragma unroll
        for (int k = 0; k < K_; k++) {
            float wk = w[k * 64 + tc];
            acc[k].x = fmaf(wk, v.x, acc[k].x);
            acc[k].y = fmaf(wk, v.y, acc[k].y);
            acc[k].z = fmaf(wk, v.z, acc[k].z);
            acc[k].w = fmaf(wk, v.w, acc[k].w);
        }
        v = vn;
    }
    float4* op = (float4*)out + (size_t)plane * (K_ * 784) + i;
    #pragma unroll
    for (int k = 0; k < K_; k++) op[(size_t)k * 784] = acc[k];
}

extern "C" void kernel_launch(void* const* d_in, const int* in_sizes, int n_in,
                              void* d_out, int out_size, void* d_ws, size_t ws_size,
                              hipStream_t stream) {
    (void)in_sizes; (void)n_in; (void)out_size; (void)ws_size;
    const float* x    = (const float*)d_in[0];
    const float* ln_w = (const float*)d_in[1];
    const float* ln_b = (const float*)d_in[2];
    const float* w1   = (const float*)d_in[3];
    const float* b1   = (const float*)d_in[4];
    const float* w2   = (const float*)d_in[5];
    const float* b2   = (const float*)d_in[6];
    float* out = (float*)d_out;
    float* ws  = (float*)d_ws;
    float* feat = ws;              // B*T*E = 65536 floats
    float* h    = ws + 65536;      // B*T*E = 65536 floats
    float* ind  = ws + 131072;     // B*K*T = 4096 floats

    hipLaunchKernelGGL(k_reduce, dim3(B_ * C_ * T_), dim3(256), 0, stream, x, feat);
    hipLaunchKernelGGL(k_mlp1,   dim3(B_ * T_),      dim3(128), 0, stream,
                       feat, ln_w, ln_b, w1, b1, h, ind);
    hipLaunchKernelGGL(k_topk,   dim3(B_ * 125),     dim3(256), 0, stream,
                       h, w2, b2, ind);
    hipLaunchKernelGGL(k_einsum, dim3(1568),         dim3(256), 0, stream, x, ind, out);
}

// Round 13
// 117.873 us; speedup vs baseline: 1.5796x; 1.0997x over previous
//
#include <hip/hip_runtime.h>
#include <math.h>

#define B_  8
#define C_  64
#define T_  64
#define HW_ 3136      // 56*56
#define E_  128
#define K_  8
#define NS_ 500

typedef float f4 __attribute__((ext_vector_type(4)));   // NT-compatible vec4

// ---------------- Kernel 1: avg+max reduce over the HW plane ----------------
// grid = B*C*T blocks, 256 threads (r5/r7 winning form). Non-temporal x reads:
// 411 MB streamed once, never re-read -> skip cache allocation.
__global__ __launch_bounds__(256) void k_reduce(const float* __restrict__ x,
                                                float* __restrict__ feat) {
    int u  = (B_ * C_ * T_ - 1) - blockIdx.x;
    int t  = u & 63;
    int bc = u >> 6;
    int c  = bc & 63;
    int b  = bc >> 6;
    const f4* p = (const f4*)(x + (size_t)u * HW_);
    float s = 0.f, m = -INFINITY;
    for (int i = threadIdx.x; i < HW_ / 4; i += 256) {
        f4 v = __builtin_nontemporal_load(p + i);
        s += v[0] + v[1] + v[2] + v[3];
        m = fmaxf(m, fmaxf(fmaxf(v[0], v[1]), fmaxf(v[2], v[3])));
    }
    for (int o = 32; o; o >>= 1) {
        s += __shfl_down(s, o);
        m = fmaxf(m, __shfl_down(m, o));
    }
    __shared__ float ss[4], sm[4];
    int wid = threadIdx.x >> 6, lane = threadIdx.x & 63;
    if (lane == 0) { ss[wid] = s; sm[wid] = m; }
    __syncthreads();
    if (threadIdx.x == 0) {
        s = ss[0] + ss[1] + ss[2] + ss[3];
        m = fmaxf(fmaxf(sm[0], sm[1]), fmaxf(sm[2], sm[3]));
        float* fr = feat + (size_t)(b * T_ + t) * E_;
        fr[c]      = s / 3136.0f;   // mean
        fr[C_ + c] = m;             // max
    }
}

// ---------------- Kernel 2: LayerNorm + matvec(128x128) + gelu --------------
// grid = B*T blocks, 128 threads (one row each). First 32 blocks also zero
// the indicator counts (4096 floats) consumed by k_topk's atomics.
__global__ __launch_bounds__(128) void k_mlp1(const float* __restrict__ feat,
                                              const float* __restrict__ ln_w,
                                              const float* __restrict__ ln_b,
                                              const float* __restrict__ w1,
                                              const float* __restrict__ b1,
                                              float* __restrict__ h,
                                              float* __restrict__ ind) {
    int r = blockIdx.x;          // b*T + t
    int j = threadIdx.x;
    if (r < 32) ind[r * 128 + j] = 0.f;
    __shared__ float nr[E_];
    __shared__ float red[2];
    float f = feat[(size_t)r * E_ + j];
    // mean
    float s = f;
    for (int o = 32; o; o >>= 1) s += __shfl_down(s, o);
    if ((j & 63) == 0) red[j >> 6] = s;
    __syncthreads();
    float mu = (red[0] + red[1]) * (1.0f / 128.0f);
    __syncthreads();
    // var
    float d = f - mu;
    s = d * d;
    for (int o = 32; o; o >>= 1) s += __shfl_down(s, o);
    if ((j & 63) == 0) red[j >> 6] = s;
    __syncthreads();
    float var = (red[0] + red[1]) * (1.0f / 128.0f);
    float n = d / sqrtf(var + 1e-5f) * ln_w[j] + ln_b[j];
    nr[j] = n;
    __syncthreads();
    float acc = b1[j];
    #pragma unroll 8
    for (int i = 0; i < E_; i++) acc = fmaf(nr[i], w1[i * E_ + j], acc);
    // exact gelu
    float g = 0.5f * acc * (1.0f + erff(acc * 0.70710678118654752f));
    h[(size_t)r * E_ + j] = g;
}

// ------- JAX-exact noise: PARTITIONABLE threefry2x32(key=(0,42)) + erfinv ---
// counts = (hi=0, lo=i); bits = out0 ^ out1 (XOR-fold, verified round 5).
__device__ inline float jax_normal(unsigned idx) {
    unsigned x0 = 0u;      // counts_hi
    unsigned x1 = idx;     // counts_lo
    const unsigned k0 = 0u, k1 = 42u;
    const unsigned k2 = 0x1BD11BDAu ^ k0 ^ k1;
    x0 += k0; x1 += k1;
#define R_(r) { x0 += x1; x1 = (x1 << r) | (x1 >> (32 - r)); x1 ^= x0; }
    R_(13) R_(15) R_(26) R_(6)
    x0 += k1; x1 += k2 + 1u;
    R_(17) R_(29) R_(16) R_(24)
    x0 += k2; x1 += k0 + 2u;
    R_(13) R_(15) R_(26) R_(6)
    x0 += k0; x1 += k1 + 3u;
    R_(17) R_(29) R_(16) R_(24)
    x0 += k1; x1 += k2 + 4u;
    R_(13) R_(15) R_(26) R_(6)
    x0 += k2; x1 += k0 + 5u;
#undef R_
    unsigned bits = x0 ^ x1;
    float f = __uint_as_float((bits >> 9) | 0x3F800000u) - 1.0f;
    const float lo = -0.99999994f;
    float u = f * 2.0f + lo;
    u = fmaxf(lo, u);
    float w = -log1pf(-u * u);
    float p;
    if (w < 5.0f) {
        w -= 2.5f;
        p = 2.81022636e-08f;
        p = fmaf(p, w, 3.43273939e-07f);
        p = fmaf(p, w, -3.5233877e-06f);
        p = fmaf(p, w, -4.39150654e-06f);
        p = fmaf(p, w, 0.00021858087f);
        p = fmaf(p, w, -0.00125372503f);
        p = fmaf(p, w, -0.00417768164f);
        p = fmaf(p, w, 0.246640727f);
        p = fmaf(p, w, 1.50140941f);
    } else {
        w = sqrtf(w) - 3.0f;
        p = -0.000200214257f;
        p = fmaf(p, w, 0.000100950558f);
        p = fmaf(p, w, 0.00134934322f);
        p = fmaf(p, w, -0.00367342844f);
        p = fmaf(p, w, 0.00573950773f);
        p = fmaf(p, w, -0.0076224613f);
        p = fmaf(p, w, 0.00943887047f);
        p = fmaf(p, w, 1.00167406f);
        p = fmaf(p, w, 2.83297682f);
    }
    return 1.41421356237f * (p * u);
}

// ------- Kernel 3 (fused): score recompute + 4 perturbed top-k samples -----
// grid = B*125 blocks, 256 threads (4 waves = 4 samples). Each block
// recomputes its b's scores from h (32 KB/b, L2-resident, shared by 125
// blocks) with the round-5 reduction order.
__global__ __launch_bounds__(256) void k_topk(const float* __restrict__ h,
                                              const float* __restrict__ w2,
                                              const float* __restrict__ b2,
                                              float* __restrict__ ind) {
    int blk  = blockIdx.x;
    int b    = blk / 125;
    int loc  = blk - b * 125;
    int tid  = threadIdx.x;
    int wid  = tid >> 6;
    int lane = tid & 63;
    __shared__ float gm[64];
    __shared__ float sv[64];
    __shared__ float gdot_s, lo_s, hi_s;
    const float* hb = h + (size_t)b * T_ * E_;

    // gmean over t of h[..., 64+i]  (serial t order == round 5)
    if (tid < 64) {
        float s = 0.f;
        for (int t = 0; t < T_; t++) s += hb[t * E_ + 64 + tid];
        gm[tid] = s * (1.0f / 64.0f);
    }
    __syncthreads();
    if (wid == 0) {
        float s = gm[lane] * w2[64 + lane];
        for (int o = 32; o; o >>= 1) s += __shfl_down(s, o);
        if (lane == 0) gdot_s = s;
    }
    __syncthreads();
    if (tid < 64) {
        float acc = 0.f;
        for (int i = 0; i < 64; i++)
            acc = fmaf(hb[tid * E_ + i], w2[i], acc);
        float pre = acc + gdot_s + b2[0];
        sv[tid] = 0.5f * pre * (1.0f + erff(pre * 0.70710678118654752f));
    }
    __syncthreads();
    if (wid == 0) {
        float v = sv[lane];
        float mn = v, mx = v;
        for (int o = 32; o; o >>= 1) {
            mn = fminf(mn, __shfl_down(mn, o));
            mx = fmaxf(mx, __shfl_down(mx, o));
        }
        if (lane == 0) { lo_s = mn; hi_s = mx; }
    }
    __syncthreads();
    float myscore = (sv[lane] - lo_s) / (hi_s - lo_s + 1e-5f);

    // one sample per wave
    int s = loc * 4 + wid;      // < 500
    float nrm = jax_normal((unsigned)((b * NS_ + s) * 64 + lane));
    float v = myscore + nrm * 0.05f;
    int rank = 0;
    for (int j = 0; j < 64; j++) {
        float o = __shfl(v, j);
        rank += (o > v) || (o == v && j < lane);
    }
    bool sel = rank < K_;
    unsigned long long m = __ballot(sel);
    if (sel) {
        int pos = __popcll(m & ((1ull << lane) - 1ull));
        atomicAdd(&ind[b * 512 + pos * 64 + lane], 1.0f);
    }
}

// ---------------- Kernel 4: weighted gather over t --------------------------
// out[b,c,k,hw] = sum_t w[b,k,t] * x[b,c,t,hw];  grid = 1568 x 256.
// Compacted active-t list + 2-deep prefetch (r10); non-temporal x reads and
// out writes (streaming, no reuse). Ascending-t order -> bit-identical sums.
__global__ __launch_bounds__(256) void k_einsum(const float* __restrict__ x,
                                                const float* __restrict__ ind,
                                                float* __restrict__ out) {
    int gid   = blockIdx.x * 256 + threadIdx.x;
    int plane = gid / 784;                  // b*C + c (b uniform per block)
    int i     = gid - plane * 784;          // float4 index in plane
    int b     = plane >> 6;
    int tid   = threadIdx.x;
    __shared__ float w[K_ * T_];
    __shared__ int   tl[T_];
    __shared__ int   nact_s;
    w[tid]       = ind[b * 512 + tid]       * (1.0f / 500.0f);
    w[tid + 256] = ind[b * 512 + 256 + tid] * (1.0f / 500.0f);
    __syncthreads();
    if (tid < 64) {          // exactly wave 0
        float s = 0.f;
        #pragma unroll
        for (int k = 0; k < K_; k++) s += w[k * 64 + tid];
        bool act = (s != 0.f);
        unsigned long long mb = __ballot(act);
        if (act) {
            int pos = __popcll(mb & ((1ull << tid) - 1ull));
            tl[pos] = tid;
        }
        if (tid == 0) nact_s = __popcll(mb);
    }
    __syncthreads();
    int nact = nact_s;

    const f4* xp = (const f4*)x + (size_t)plane * (T_ * 784) + i;
    f4 acc[K_];
    #pragma unroll
    for (int k = 0; k < K_; k++) acc[k] = (f4){0.f, 0.f, 0.f, 0.f};

    f4 v = __builtin_nontemporal_load(xp + (size_t)tl[0] * 784);
    for (int j = 0; j < nact; j++) {
        int tc = tl[j];
        f4 vn = v;
        if (j + 1 < nact)
            vn = __builtin_nontemporal_load(xp + (size_t)tl[j + 1] * 784);
        #pragma unroll
        for (int k = 0; k < K_; k++) {
            float wk = w[k * 64 + tc];
            acc[k][0] = fmaf(wk, v[0], acc[k][0]);
            acc[k][1] = fmaf(wk, v[1], acc[k][1]);
            acc[k][2] = fmaf(wk, v[2], acc[k][2]);
            acc[k][3] = fmaf(wk, v[3], acc[k][3]);
        }
        v = vn;
    }
    f4* op = (f4*)out + (size_t)plane * (K_ * 784) + i;
    #pragma unroll
    for (int k = 0; k < K_; k++)
        __builtin_nontemporal_store(acc[k], op + (size_t)k * 784);
}

extern "C" void kernel_launch(void* const* d_in, const int* in_sizes, int n_in,
                              void* d_out, int out_size, void* d_ws, size_t ws_size,
                              hipStream_t stream) {
    (void)in_sizes; (void)n_in; (void)out_size; (void)ws_size;
    const float* x    = (const float*)d_in[0];
    const float* ln_w = (const float*)d_in[1];
    const float* ln_b = (const float*)d_in[2];
    const float* w1   = (const float*)d_in[3];
    const float* b1   = (const float*)d_in[4];
    const float* w2   = (const float*)d_in[5];
    const float* b2   = (const float*)d_in[6];
    float* out = (float*)d_out;
    float* ws  = (float*)d_ws;
    float* feat = ws;              // B*T*E = 65536 floats
    float* h    = ws + 65536;      // B*T*E = 65536 floats
    float* ind  = ws + 131072;     // B*K*T = 4096 floats

    hipLaunchKernelGGL(k_reduce, dim3(B_ * C_ * T_), dim3(256), 0, stream, x, feat);
    hipLaunchKernelGGL(k_mlp1,   dim3(B_ * T_),      dim3(128), 0, stream,
                       feat, ln_w, ln_b, w1, b1, h, ind);
    hipLaunchKernelGGL(k_topk,   dim3(B_ * 125),     dim3(256), 0, stream,
                       h, w2, b2, ind);
    hipLaunchKernelGGL(k_einsum, dim3(1568),         dim3(256), 0, stream, x, ind, out);
}